// Round 8
// baseline (315.147 us; speedup 1.0000x reference)
//
#include <hip/hip_runtime.h>
#include <hip/hip_fp16.h>
#include <stdint.h>

#define N_NODES 50000
#define NC 4        // source chunks
#define CHUNK 12500 // nodes/chunk: hs slice = 12500*256B = 3.2MB < 4MB XCD L2
#define SCAP 32     // per-chunk sub-bucket capacity (deg/chunk ~Pois(4), P(>32)~1e-17)
#define ROWS 128    // bucket row in ushorts = NC*SCAP
#define ROWU 64     // bucket row in uints
#define NPW 8       // nodes per wave in layer-2 (slot-interleaved)

// ---------------------------------------------------------------------------
// zero cursor4 (4 sub-counters per node) + fold weight constants into pc.
//  pc[0..1023]    M0 = Wc2[0]@Wl2[0][:32]      pc[1024..2047]  M2 (gate 2)
//  pc[2048..2079] w0 = bc2[0]@Wl2[0]+bl2[0]    pc[2080..2111]  w2
//  pc[2112..2143] uz = Wc1[0]@Wl1[0]           pc[2144..2175]  vz
//  pc[2176..2207] uh (gate 2)                  pc[2208..2239]  vh
// (H=0 => reset gate dead; concat uses only rows 0..31 of each Wl)
// ---------------------------------------------------------------------------
__global__ void zero_precomp_kernel(int* __restrict__ cursor4,
                                    const float* __restrict__ Wc1,
                                    const float* __restrict__ bc1,
                                    const float* __restrict__ Wl1,
                                    const float* __restrict__ bl1,
                                    const float* __restrict__ Wc2,
                                    const float* __restrict__ bc2,
                                    const float* __restrict__ Wl2,
                                    const float* __restrict__ bl2,
                                    float* __restrict__ pc, int N4) {
    int i = blockIdx.x * blockDim.x + threadIdx.x;
    if (i < N4) cursor4[i] = 0;
    if (i >= 2240) return;
    if (i < 2048) {
        int g = i >> 10;
        int kf = i & 1023;
        int k = kf >> 5, f = kf & 31;
        int gate = g ? 2 : 0;
        float s = 0.0f;
        for (int j = 0; j < 32; ++j)
            s += Wc2[gate * 1024 + k * 32 + j] * Wl2[gate * 2048 + j * 32 + f];
        pc[i] = s;
    } else if (i < 2112) {
        int g = (i - 2048) >> 5;
        int f = i & 31;
        int gate = g ? 2 : 0;
        float s = bl2[gate * 32 + f];
        for (int j = 0; j < 32; ++j)
            s += bc2[gate * 32 + j] * Wl2[gate * 2048 + j * 32 + f];
        pc[i] = s;
    } else {
        int t = i - 2112;
        int which = t >> 5;
        int f = t & 31;
        int gate = (which >= 2) ? 2 : 0;
        if ((which & 1) == 0) {
            float s = 0.0f;
            for (int j = 0; j < 32; ++j)
                s += Wc1[gate * 32 + j] * Wl1[gate * 2048 + j * 32 + f];
            pc[i] = s;
        } else {
            float s = bl1[gate * 32 + f];
            for (int j = 0; j < 32; ++j)
                s += bc1[gate * 32 + j] * Wl1[gate * 2048 + j * 32 + f];
            pc[i] = s;
        }
    }
}

// ---------------------------------------------------------------------------
// Chunk-sorted bucket build: bucket[d][c][pos] = src, c = src/CHUNK.
// After: cursor4[d*4+c] = per-chunk in-degree (uncapped).
// ---------------------------------------------------------------------------
__global__ void fill_kernel(const int* __restrict__ src,
                            const int* __restrict__ dst,
                            int* __restrict__ cursor4,
                            unsigned short* __restrict__ bucket, int E) {
    int e = blockIdx.x * blockDim.x + threadIdx.x;
    if (e < E) {
        int s = src[e];
        int d = dst[e];
        int c = (unsigned)s / (unsigned)CHUNK;  // magic-mul (const divisor)
        int pos = atomicAdd(&cursor4[d * 4 + c], 1);
        if (pos < SCAP) bucket[(size_t)d * ROWS + c * SCAP + pos] = (unsigned short)s;
    }
}

// dis[n] = rsqrt(deg+1);  xd[n] = float4{x[b,n]*dis[n]}
__global__ void dis_xd_kernel(const int4* __restrict__ cursor4,
                              const float* __restrict__ x,
                              float* __restrict__ dis,
                              float4* __restrict__ xd, int N) {
    int n = blockIdx.x * blockDim.x + threadIdx.x;
    if (n >= N) return;
    int4 cc = cursor4[n];
    int deg = cc.x + cc.y + cc.z + cc.w;
    float d = rsqrtf((float)(deg + 1));
    dis[n] = d;
    xd[n] = make_float4(x[n] * d, x[N + n] * d, x[2 * N + n] * d,
                        x[3 * N + n] * d);
}

// ---------------------------------------------------------------------------
// Fused layer 1: rank-1 agg (8 lanes/node over the 4 sub-buckets, xor-reduce)
// + folded gates -> hs[n][f][b] fp16.
// ---------------------------------------------------------------------------
__global__ void s1h1_kernel(const float4* __restrict__ xd,
                            const float* __restrict__ dis,
                            const int4* __restrict__ cursor4,
                            const unsigned short* __restrict__ bucket,
                            const float* __restrict__ pc,
                            char* __restrict__ hs, int N) {
    int idx = blockIdx.x * blockDim.x + threadIdx.x;
    int node = idx >> 3;
    if (node >= N) return;
    int j = idx & 7;
    int4 cc = cursor4[node];
    int cn[4] = {min(cc.x, SCAP), min(cc.y, SCAP), min(cc.z, SCAP),
                 min(cc.w, SCAP)};
    float ax, ay, az, aw;
    if (j == 0) {
        float4 v = xd[node];  // self loop
        ax = v.x; ay = v.y; az = v.z; aw = v.w;
    } else {
        ax = ay = az = aw = 0.f;
    }
#pragma unroll
    for (int c = 0; c < NC; ++c) {
        int cnt = cn[c];
        for (int i = j; i < cnt; i += 8) {
            int s = bucket[(size_t)node * ROWS + c * SCAP + i];
            float4 v = xd[s];
            ax += v.x; ay += v.y; az += v.z; aw += v.w;
        }
    }
#pragma unroll
    for (int m = 4; m; m >>= 1) {
        ax += __shfl_xor(ax, m, 64);
        ay += __shfl_xor(ay, m, 64);
        az += __shfl_xor(az, m, 64);
        aw += __shfl_xor(aw, m, 64);
    }
    float d = dis[node];
    float t0 = ax * d, t1 = ay * d, t2 = az * d, t3 = aw * d;
#pragma unroll
    for (int m = 0; m < 4; ++m) {
        int f = j + 8 * m;
        float uz = pc[2112 + f], vz = pc[2144 + f];
        float uh = pc[2176 + f], vh = pc[2208 + f];
        float h0 = fmaxf((1.0f - 1.0f / (1.0f + expf(-(t0 * uz + vz)))) *
                         tanhf(t0 * uh + vh), 0.0f) * d;
        float h1 = fmaxf((1.0f - 1.0f / (1.0f + expf(-(t1 * uz + vz)))) *
                         tanhf(t1 * uh + vh), 0.0f) * d;
        float h2 = fmaxf((1.0f - 1.0f / (1.0f + expf(-(t2 * uz + vz)))) *
                         tanhf(t2 * uh + vh), 0.0f) * d;
        float h3 = fmaxf((1.0f - 1.0f / (1.0f + expf(-(t3 * uz + vz)))) *
                         tanhf(t3 * uh + vh), 0.0f) * d;
        __half2 lo = __floats2half2_rn(h0, h1);
        __half2 hi = __floats2half2_rn(h2, h3);
        uint2 u;
        u.x = *reinterpret_cast<unsigned int*>(&lo);
        u.y = *reinterpret_cast<unsigned int*>(&hi);
        *reinterpret_cast<uint2*>(hs + (size_t)node * 256 + f * 8) = u;
    }
}

// ---------------------------------------------------------------------------
// Layer-2: chunk-phased, slot-interleaved gather + gates + output projection.
// Wave owns NPW=8 nodes (named regs: acc/bidx/counts per node, rule-#20 safe).
// Pass c gathers ONLY from hs chunk c (3.2MB, L2-resident per XCD).
// Inner loop over slots issues 1 load per node per slot -> ~8 loads in flight.
// Tail per node: wave-private LDS transpose + dual-gate matvec (R7, proven).
// ---------------------------------------------------------------------------
__global__ __launch_bounds__(256) void l2_agg_kernel(
    const char* __restrict__ hs, const float* __restrict__ dis,
    const int4* __restrict__ cursor4, const uint32_t* __restrict__ bucket,
    const float* __restrict__ pc, const float* __restrict__ Wout,
    const float* __restrict__ bout, float* __restrict__ out, int N) {
    __shared__ float2 sT[4][64];  // wave-private transpose scratch
    int wv = threadIdx.x >> 6;
    int lane = threadIdx.x & 63;
    int f = lane & 31;
    int h = lane >> 5;

    float wl0[32], wl2[32];
#pragma unroll
    for (int k = 0; k < 32; ++k) {
        wl0[k] = pc[k * 32 + f];
        wl2[k] = pc[1024 + k * 32 + f];
    }
    float w0 = pc[2048 + f], w2 = pc[2080 + f];
    float wf = Wout[f];
    float bo = bout[0];
    const char* hp = hs + f * 8 + h * 4;  // lane's half2 within a 256B row

    int wid = (blockIdx.x * blockDim.x + threadIdx.x) >> 6;
    int n0 = wid * NPW;
    if (n0 >= N) return;

    // per-node state in named registers
#define DECL(J)                                                              \
    __half2 acc##J = __floats2half2_rn(0.f, 0.f);                            \
    uint32_t bx##J = 0, cp##J = 0;                                           \
    int cs##J = 0;                                                           \
    {                                                                        \
        int n = n0 + J;                                                      \
        if (n < N) {                                                         \
            int4 cc = cursor4[n];                                            \
            int a0 = min(cc.x, SCAP), a1 = min(cc.y, SCAP);                  \
            int a2 = min(cc.z, SCAP), a3 = min(cc.w, SCAP);                  \
            cp##J = (uint32_t)(a0 | (a1 << 8) | (a2 << 16) | (a3 << 24));    \
            bx##J = bucket[(size_t)n * ROWU + lane];                         \
            cs##J = (int)((unsigned)n / (unsigned)CHUNK);                    \
        }                                                                    \
    }
    DECL(0) DECL(1) DECL(2) DECL(3) DECL(4) DECL(5) DECL(6) DECL(7)
#undef DECL

    for (int c = 0; c < NC; ++c) {
        int lb = c * 16;  // uint lane base of this sub-bucket in the row
        // self-loop term lands in its own chunk's pass (row is L2-warm)
#define SELF(J)                                                              \
    {                                                                        \
        int n = n0 + J;                                                      \
        if (n < N && cs##J == c)                                             \
            acc##J = __hadd2(acc##J,                                         \
                             *(const __half2*)(hp + (size_t)n * 256));       \
    }
        SELF(0) SELF(1) SELF(2) SELF(3) SELF(4) SELF(5) SELF(6) SELF(7)
#undef SELF
        int c0_ = (int)((cp0 >> (8 * c)) & 255u);
        int c1_ = (int)((cp1 >> (8 * c)) & 255u);
        int c2_ = (int)((cp2 >> (8 * c)) & 255u);
        int c3_ = (int)((cp3 >> (8 * c)) & 255u);
        int c4_ = (int)((cp4 >> (8 * c)) & 255u);
        int c5_ = (int)((cp5 >> (8 * c)) & 255u);
        int c6_ = (int)((cp6 >> (8 * c)) & 255u);
        int c7_ = (int)((cp7 >> (8 * c)) & 255u);
        int mc = max(max(max(c0_, c1_), max(c2_, c3_)),
                     max(max(c4_, c5_), max(c6_, c7_)));
        for (int s_ = 0; s_ < mc; ++s_) {
            int w_ = lb + (s_ >> 1);
            int hi = s_ & 1;
#define EDGE(J)                                                              \
    if (s_ < c##J##_) {                                                      \
        uint32_t ww = __builtin_amdgcn_readlane(bx##J, w_);                  \
        uint32_t ix = hi ? (ww >> 16) : (ww & 0xffffu);                      \
        acc##J = __hadd2(acc##J, *(const __half2*)(hp + ix * 256u));         \
    }
            EDGE(0) EDGE(1) EDGE(2) EDGE(3) EDGE(4) EDGE(5) EDGE(6) EDGE(7)
#undef EDGE
        }
    }

    // tails: LDS transpose (wave-private, in-order DS => no barrier) + gates
#define TAIL(J)                                                              \
    {                                                                        \
        int n = n0 + J;                                                      \
        if (n < N) {                                                         \
            float2 fa = __half22float2(acc##J);                              \
            sT[wv][lane] = fa;                                               \
            float sz0 = 0.f, sz1 = 0.f, sh0 = 0.f, sh1 = 0.f;                \
            const float2* tp = &sT[wv][h * 32];                              \
            _Pragma("unroll") for (int k = 0; k < 32; k += 2) {              \
                float4 t2 = *(const float4*)&tp[k];                          \
                sz0 += t2.x * wl0[k];     sz1 += t2.y * wl0[k];              \
                sh0 += t2.x * wl2[k];     sh1 += t2.y * wl2[k];              \
                sz0 += t2.z * wl0[k + 1]; sz1 += t2.w * wl0[k + 1];          \
                sh0 += t2.z * wl2[k + 1]; sh1 += t2.w * wl2[k + 1];          \
            }                                                                \
            float dn = dis[n];                                               \
            float z0 = 1.0f / (1.0f + expf(-(dn * sz0 + w0)));               \
            float z1 = 1.0f / (1.0f + expf(-(dn * sz1 + w0)));               \
            float t0 = tanhf(dn * sh0 + w2);                                 \
            float t1 = tanhf(dn * sh1 + w2);                                 \
            float h20 = fmaxf((1.0f - z0) * t0, 0.0f);                       \
            float h21 = fmaxf((1.0f - z1) * t1, 0.0f);                       \
            float o0 = h20 * wf;                                             \
            float o1 = h21 * wf;                                             \
            _Pragma("unroll") for (int d_ = 16; d_; d_ >>= 1) {              \
                o0 += __shfl_xor(o0, d_, 64);                                \
                o1 += __shfl_xor(o1, d_, 64);                                \
            }                                                                \
            if (f == 0) {                                                    \
                out[(size_t)(2 * h) * N + n] = o0 + bo;                      \
                out[(size_t)(2 * h + 1) * N + n] = o1 + bo;                  \
            }                                                                \
        }                                                                    \
    }
    TAIL(0) TAIL(1) TAIL(2) TAIL(3) TAIL(4) TAIL(5) TAIL(6) TAIL(7)
#undef TAIL
}

// ---------------------------------------------------------------------------

extern "C" void kernel_launch(void* const* d_in, const int* in_sizes, int n_in,
                              void* d_out, int out_size, void* d_ws,
                              size_t ws_size, hipStream_t stream) {
    const float* x    = (const float*)d_in[0];
    const int*   ei   = (const int*)d_in[1];
    const float* Wc1  = (const float*)d_in[2];
    const float* bc1  = (const float*)d_in[3];
    const float* Wl1  = (const float*)d_in[4];
    const float* bl1  = (const float*)d_in[5];
    // d_in[6] att1: softmax over 1 element == 1.0
    const float* Wc2  = (const float*)d_in[7];
    const float* bc2  = (const float*)d_in[8];
    const float* Wl2  = (const float*)d_in[9];
    const float* bl2  = (const float*)d_in[10];
    // d_in[11] att2 unused
    const float* Wout = (const float*)d_in[12];
    const float* bout = (const float*)d_in[13];

    const int E = in_sizes[1] / 2;
    const int N = N_NODES;
    const int* src = ei;
    const int* dst = ei + E;

    char* p = (char*)d_ws;
    auto alloc = [&](size_t bytes) {
        char* r = p;
        p += (bytes + 15) & ~(size_t)15;
        return r;
    };
    int*            cursor4 = (int*)alloc((size_t)N * 4 * sizeof(int));
    unsigned short* bucket  = (unsigned short*)alloc((size_t)N * ROWS * 2);
    float*          dis     = (float*)alloc(N * sizeof(float));
    float*          xd      = (float*)alloc((size_t)N * 4 * sizeof(float));
    char*           hs      = (char*)alloc((size_t)N * 256);  // fp16 [n][f][b]
    float*          pc      = (float*)alloc(2240 * sizeof(float));

    // 1) zero cursor4 + fold constants
    zero_precomp_kernel<<<(4 * N + 255) / 256, 256, 0, stream>>>(
        cursor4, Wc1, bc1, Wl1, bl1, Wc2, bc2, Wl2, bl2, pc, 4 * N);

    // 2) chunk-sorted bucket build
    fill_kernel<<<(E + 255) / 256, 256, 0, stream>>>(src, dst, cursor4, bucket,
                                                     E);
    // 3) dis + xd
    dis_xd_kernel<<<(N + 255) / 256, 256, 0, stream>>>((const int4*)cursor4, x,
                                                       dis, (float4*)xd, N);
    // 4) layer 1 fused (agg + gates -> fp16 hs)
    s1h1_kernel<<<(N * 8 + 255) / 256, 256, 0, stream>>>(
        (const float4*)xd, dis, (const int4*)cursor4, bucket, pc, hs, N);

    // 5) layer 2: chunk-phased gather (NPW nodes per wave)
    int blocks = (N + NPW * 4 - 1) / (NPW * 4);
    l2_agg_kernel<<<blocks, 256, 0, stream>>>(
        hs, dis, (const int4*)cursor4, (const uint32_t*)bucket, pc, Wout, bout,
        (float*)d_out, N);
}

// Round 11
// 212.801 us; speedup vs baseline: 1.4809x; 1.4809x over previous
//
#include <hip/hip_runtime.h>
#include <hip/hip_fp16.h>
#include <stdint.h>

#define N_NODES 50000
#define BATCH 4
#define CAP 64  // max in-degree (deg ~ Poisson(16); P(>64) ~ 1e-10)

// ---------------------------------------------------------------------------
// Merged: zero cursor + fold weight constants into pc.
//  pc[0..1023]    M0 = Wc2[0]@Wl2[0][:32]      pc[1024..2047]  M2 (gate 2)
//  pc[2048..2079] w0 = bc2[0]@Wl2[0]+bl2[0]    pc[2080..2111]  w2
//  pc[2112..2143] uz = Wc1[0]@Wl1[0]           pc[2144..2175]  vz
//  pc[2176..2207] uh (gate 2)                  pc[2208..2239]  vh
// (H=0 => reset gate dead; concat uses only rows 0..31 of each Wl)
// ---------------------------------------------------------------------------
__global__ void zero_precomp_kernel(int* __restrict__ cursor,
                                    const float* __restrict__ Wc1,
                                    const float* __restrict__ bc1,
                                    const float* __restrict__ Wl1,
                                    const float* __restrict__ bl1,
                                    const float* __restrict__ Wc2,
                                    const float* __restrict__ bc2,
                                    const float* __restrict__ Wl2,
                                    const float* __restrict__ bl2,
                                    float* __restrict__ pc, int N) {
    int i = blockIdx.x * blockDim.x + threadIdx.x;
    if (i < N) cursor[i] = 0;
    if (i >= 2240) return;
    if (i < 2048) {
        int g = i >> 10;
        int kf = i & 1023;
        int k = kf >> 5, f = kf & 31;
        int gate = g ? 2 : 0;
        float s = 0.0f;
        for (int j = 0; j < 32; ++j)
            s += Wc2[gate * 1024 + k * 32 + j] * Wl2[gate * 2048 + j * 32 + f];
        pc[i] = s;
    } else if (i < 2112) {
        int g = (i - 2048) >> 5;
        int f = i & 31;
        int gate = g ? 2 : 0;
        float s = bl2[gate * 32 + f];
        for (int j = 0; j < 32; ++j)
            s += bc2[gate * 32 + j] * Wl2[gate * 2048 + j * 32 + f];
        pc[i] = s;
    } else {
        int t = i - 2112;
        int which = t >> 5;
        int f = t & 31;
        int gate = (which >= 2) ? 2 : 0;
        if ((which & 1) == 0) {
            float s = 0.0f;
            for (int j = 0; j < 32; ++j)
                s += Wc1[gate * 32 + j] * Wl1[gate * 2048 + j * 32 + f];
            pc[i] = s;
        } else {
            float s = bl1[gate * 32 + f];
            for (int j = 0; j < 32; ++j)
                s += bc1[gate * 32 + j] * Wl1[gate * 2048 + j * 32 + f];
            pc[i] = s;
        }
    }
}

// ---------------------------------------------------------------------------
// Bucket CSR build: bucket[d][pos] = src (ushort). After: cursor[d] = deg(d).
// ---------------------------------------------------------------------------
__global__ void fill_kernel(const int* __restrict__ src,
                            const int* __restrict__ dst,
                            int* __restrict__ cursor,
                            unsigned short* __restrict__ bucket, int E) {
    int e = blockIdx.x * blockDim.x + threadIdx.x;
    if (e < E) {
        int d = dst[e];
        int pos = atomicAdd(&cursor[d], 1);
        if (pos < CAP) bucket[d * CAP + pos] = (unsigned short)src[e];
    }
}

// dis[n] = rsqrt(deg+1);  xd[n] = float4{x[b,n]*dis[n]}
__global__ void dis_xd_kernel(const int* __restrict__ deg,
                              const float* __restrict__ x,
                              float* __restrict__ dis,
                              float4* __restrict__ xd, int N) {
    int n = blockIdx.x * blockDim.x + threadIdx.x;
    if (n >= N) return;
    float d = rsqrtf((float)(deg[n] + 1));
    dis[n] = d;
    xd[n] = make_float4(x[n] * d, x[N + n] * d, x[2 * N + n] * d,
                        x[3 * N + n] * d);
}

// ---------------------------------------------------------------------------
// Fused layer 1: scalar agg (8 lanes/node, xor-reduce) + folded gates,
// writing hs[n][f][b] as fp16 (values ~3e-3 scale).
// ---------------------------------------------------------------------------
__global__ void s1h1_kernel(const float4* __restrict__ xd,
                            const float* __restrict__ dis,
                            const int* __restrict__ deg,
                            const unsigned short* __restrict__ bucket,
                            const float* __restrict__ pc,
                            char* __restrict__ hs, int N) {
    int idx = blockIdx.x * blockDim.x + threadIdx.x;
    int node = idx >> 3;
    if (node >= N) return;
    int j = idx & 7;
    int cnt = deg[node];
    if (cnt > CAP) cnt = CAP;
    float ax, ay, az, aw;
    if (j == 0) {
        float4 v = xd[node];  // self loop
        ax = v.x; ay = v.y; az = v.z; aw = v.w;
    } else {
        ax = ay = az = aw = 0.f;
    }
    for (int i = j; i < cnt; i += 8) {
        int s = bucket[node * CAP + i];
        float4 v = xd[s];
        ax += v.x; ay += v.y; az += v.z; aw += v.w;
    }
#pragma unroll
    for (int m = 4; m; m >>= 1) {
        ax += __shfl_xor(ax, m, 64);
        ay += __shfl_xor(ay, m, 64);
        az += __shfl_xor(az, m, 64);
        aw += __shfl_xor(aw, m, 64);
    }
    float d = dis[node];
    float t0 = ax * d, t1 = ay * d, t2 = az * d, t3 = aw * d;
#pragma unroll
    for (int m = 0; m < 4; ++m) {
        int f = j + 8 * m;
        float uz = pc[2112 + f], vz = pc[2144 + f];
        float uh = pc[2176 + f], vh = pc[2208 + f];
        float h0 = fmaxf((1.0f - 1.0f / (1.0f + expf(-(t0 * uz + vz)))) *
                         tanhf(t0 * uh + vh), 0.0f) * d;
        float h1 = fmaxf((1.0f - 1.0f / (1.0f + expf(-(t1 * uz + vz)))) *
                         tanhf(t1 * uh + vh), 0.0f) * d;
        float h2 = fmaxf((1.0f - 1.0f / (1.0f + expf(-(t2 * uz + vz)))) *
                         tanhf(t2 * uh + vh), 0.0f) * d;
        float h3 = fmaxf((1.0f - 1.0f / (1.0f + expf(-(t3 * uz + vz)))) *
                         tanhf(t3 * uh + vh), 0.0f) * d;
        __half2 lo = __floats2half2_rn(h0, h1);
        __half2 hi = __floats2half2_rn(h2, h3);
        uint2 u;
        u.x = *reinterpret_cast<unsigned int*>(&lo);
        u.y = *reinterpret_cast<unsigned int*>(&hi);
        *reinterpret_cast<uint2*>(hs + (size_t)node * 256 + f * 8) = u;
    }
}

// ---------------------------------------------------------------------------
// Layer-2 fused agg + gates + output projection. Grid-stride waves.
// Wave = node. Lane l: f=l&31, h=l>>5 owns batches {2h,2h+1} (half2 4B/edge).
// Edge loop: 16/8/4/1 ladder -> up to 16 outstanding loads per wave
// (R8 lesson: this window, not L2 blocking, is the testable lever).
// Tail: both gates' M-columns in VGPRs + wave-private LDS transpose (R7).
// ---------------------------------------------------------------------------
__global__ __launch_bounds__(256) void l2_agg_kernel(
    const char* __restrict__ hs, const float* __restrict__ dis,
    const int* __restrict__ deg, const unsigned short* __restrict__ bucket,
    const float* __restrict__ pc, const float* __restrict__ Wout,
    const float* __restrict__ bout, float* __restrict__ out, int N) {
    __shared__ float2 sT[4][64];  // wave-private transpose scratch
    int wv = threadIdx.x >> 6;
    int lane = threadIdx.x & 63;
    int f = lane & 31;
    int h = lane >> 5;

    float wl0[32], wl2[32];
#pragma unroll
    for (int k = 0; k < 32; ++k) {
        wl0[k] = pc[k * 32 + f];          // M0 column f
        wl2[k] = pc[1024 + k * 32 + f];   // M2 column f
    }
    float w0 = pc[2048 + f], w2 = pc[2080 + f];
    float wf = Wout[f];
    float bo = bout[0];
    const char* hp = hs + f * 8 + h * 4;  // lane's half2 within a 256B row

    int wid = (blockIdx.x * blockDim.x + threadIdx.x) >> 6;
    int nw = (gridDim.x * blockDim.x) >> 6;

    for (int node = wid; node < N; node += nw) {
        int cnt = deg[node];
        if (cnt > CAP) cnt = CAP;
        unsigned int bidx = bucket[node * CAP + lane];  // 128B/wave coalesced
        __half2 acc = *(const __half2*)(hp + (size_t)node * 256);  // self loop
        int i = 0;
        for (; i + 16 <= cnt; i += 16) {
            unsigned int o0 = __builtin_amdgcn_readlane(bidx, i) * 256u;
            unsigned int o1 = __builtin_amdgcn_readlane(bidx, i + 1) * 256u;
            unsigned int o2 = __builtin_amdgcn_readlane(bidx, i + 2) * 256u;
            unsigned int o3 = __builtin_amdgcn_readlane(bidx, i + 3) * 256u;
            unsigned int o4 = __builtin_amdgcn_readlane(bidx, i + 4) * 256u;
            unsigned int o5 = __builtin_amdgcn_readlane(bidx, i + 5) * 256u;
            unsigned int o6 = __builtin_amdgcn_readlane(bidx, i + 6) * 256u;
            unsigned int o7 = __builtin_amdgcn_readlane(bidx, i + 7) * 256u;
            unsigned int o8 = __builtin_amdgcn_readlane(bidx, i + 8) * 256u;
            unsigned int o9 = __builtin_amdgcn_readlane(bidx, i + 9) * 256u;
            unsigned int oa = __builtin_amdgcn_readlane(bidx, i + 10) * 256u;
            unsigned int ob = __builtin_amdgcn_readlane(bidx, i + 11) * 256u;
            unsigned int oc = __builtin_amdgcn_readlane(bidx, i + 12) * 256u;
            unsigned int od = __builtin_amdgcn_readlane(bidx, i + 13) * 256u;
            unsigned int oe = __builtin_amdgcn_readlane(bidx, i + 14) * 256u;
            unsigned int of_ = __builtin_amdgcn_readlane(bidx, i + 15) * 256u;
            __half2 v0 = *(const __half2*)(hp + o0);
            __half2 v1 = *(const __half2*)(hp + o1);
            __half2 v2 = *(const __half2*)(hp + o2);
            __half2 v3 = *(const __half2*)(hp + o3);
            __half2 v4 = *(const __half2*)(hp + o4);
            __half2 v5 = *(const __half2*)(hp + o5);
            __half2 v6 = *(const __half2*)(hp + o6);
            __half2 v7 = *(const __half2*)(hp + o7);
            __half2 v8 = *(const __half2*)(hp + o8);
            __half2 v9 = *(const __half2*)(hp + o9);
            __half2 va = *(const __half2*)(hp + oa);
            __half2 vb = *(const __half2*)(hp + ob);
            __half2 vc = *(const __half2*)(hp + oc);
            __half2 vd = *(const __half2*)(hp + od);
            __half2 ve = *(const __half2*)(hp + oe);
            __half2 vf = *(const __half2*)(hp + of_);
            __half2 s01 = __hadd2(v0, v1), s23 = __hadd2(v2, v3);
            __half2 s45 = __hadd2(v4, v5), s67 = __hadd2(v6, v7);
            __half2 s89 = __hadd2(v8, v9), sab = __hadd2(va, vb);
            __half2 scd = __hadd2(vc, vd), sef = __hadd2(ve, vf);
            __half2 t03 = __hadd2(s01, s23), t47 = __hadd2(s45, s67);
            __half2 t8b = __hadd2(s89, sab), tcf = __hadd2(scd, sef);
            acc = __hadd2(acc, __hadd2(__hadd2(t03, t47), __hadd2(t8b, tcf)));
        }
        if (i + 8 <= cnt) {
            unsigned int o0 = __builtin_amdgcn_readlane(bidx, i) * 256u;
            unsigned int o1 = __builtin_amdgcn_readlane(bidx, i + 1) * 256u;
            unsigned int o2 = __builtin_amdgcn_readlane(bidx, i + 2) * 256u;
            unsigned int o3 = __builtin_amdgcn_readlane(bidx, i + 3) * 256u;
            unsigned int o4 = __builtin_amdgcn_readlane(bidx, i + 4) * 256u;
            unsigned int o5 = __builtin_amdgcn_readlane(bidx, i + 5) * 256u;
            unsigned int o6 = __builtin_amdgcn_readlane(bidx, i + 6) * 256u;
            unsigned int o7 = __builtin_amdgcn_readlane(bidx, i + 7) * 256u;
            __half2 v0 = *(const __half2*)(hp + o0);
            __half2 v1 = *(const __half2*)(hp + o1);
            __half2 v2 = *(const __half2*)(hp + o2);
            __half2 v3 = *(const __half2*)(hp + o3);
            __half2 v4 = *(const __half2*)(hp + o4);
            __half2 v5 = *(const __half2*)(hp + o5);
            __half2 v6 = *(const __half2*)(hp + o6);
            __half2 v7 = *(const __half2*)(hp + o7);
            __half2 s01 = __hadd2(v0, v1), s23 = __hadd2(v2, v3);
            __half2 s45 = __hadd2(v4, v5), s67 = __hadd2(v6, v7);
            acc = __hadd2(acc, __hadd2(__hadd2(s01, s23), __hadd2(s45, s67)));
            i += 8;
        }
        if (i + 4 <= cnt) {
            unsigned int o0 = __builtin_amdgcn_readlane(bidx, i) * 256u;
            unsigned int o1 = __builtin_amdgcn_readlane(bidx, i + 1) * 256u;
            unsigned int o2 = __builtin_amdgcn_readlane(bidx, i + 2) * 256u;
            unsigned int o3 = __builtin_amdgcn_readlane(bidx, i + 3) * 256u;
            __half2 v0 = *(const __half2*)(hp + o0);
            __half2 v1 = *(const __half2*)(hp + o1);
            __half2 v2 = *(const __half2*)(hp + o2);
            __half2 v3 = *(const __half2*)(hp + o3);
            acc = __hadd2(acc, __hadd2(__hadd2(v0, v1), __hadd2(v2, v3)));
            i += 4;
        }
        for (; i < cnt; ++i) {
            unsigned int o = __builtin_amdgcn_readlane(bidx, i) * 256u;
            acc = __hadd2(acc, *(const __half2*)(hp + o));
        }
        float2 fa = __half22float2(acc);  // (T[2h][f], T[2h+1][f])

        // transpose via wave-private LDS (no barrier; in-wave DS ordering)
        sT[wv][lane] = fa;

        float sz0 = 0.f, sz1 = 0.f, sh0 = 0.f, sh1 = 0.f;
        const float2* tp = &sT[wv][h * 32];  // this half's 32 (T0,T1) pairs
#pragma unroll
        for (int k = 0; k < 32; k += 2) {
            float4 t2 = *(const float4*)&tp[k];  // broadcast read, 2 k's
            sz0 += t2.x * wl0[k];     sz1 += t2.y * wl0[k];
            sh0 += t2.x * wl2[k];     sh1 += t2.y * wl2[k];
            sz0 += t2.z * wl0[k + 1]; sz1 += t2.w * wl0[k + 1];
            sh0 += t2.z * wl2[k + 1]; sh1 += t2.w * wl2[k + 1];
        }
        float dn = dis[node];
        float z0 = 1.0f / (1.0f + expf(-(dn * sz0 + w0)));
        float z1 = 1.0f / (1.0f + expf(-(dn * sz1 + w0)));
        float t0 = tanhf(dn * sh0 + w2);
        float t1 = tanhf(dn * sh1 + w2);
        float h20 = fmaxf((1.0f - z0) * t0, 0.0f);
        float h21 = fmaxf((1.0f - z1) * t1, 0.0f);

        float o0 = h20 * wf;
        float o1 = h21 * wf;
#pragma unroll
        for (int d = 16; d; d >>= 1) {  // reduce over f within each half
            o0 += __shfl_xor(o0, d, 64);
            o1 += __shfl_xor(o1, d, 64);
        }
        if (f == 0) {
            out[(size_t)(2 * h) * N + node] = o0 + bo;
            out[(size_t)(2 * h + 1) * N + node] = o1 + bo;
        }
    }
}

// ---------------------------------------------------------------------------

extern "C" void kernel_launch(void* const* d_in, const int* in_sizes, int n_in,
                              void* d_out, int out_size, void* d_ws,
                              size_t ws_size, hipStream_t stream) {
    const float* x    = (const float*)d_in[0];
    const int*   ei   = (const int*)d_in[1];
    const float* Wc1  = (const float*)d_in[2];
    const float* bc1  = (const float*)d_in[3];
    const float* Wl1  = (const float*)d_in[4];
    const float* bl1  = (const float*)d_in[5];
    // d_in[6] att1: softmax over 1 element == 1.0
    const float* Wc2  = (const float*)d_in[7];
    const float* bc2  = (const float*)d_in[8];
    const float* Wl2  = (const float*)d_in[9];
    const float* bl2  = (const float*)d_in[10];
    // d_in[11] att2 unused
    const float* Wout = (const float*)d_in[12];
    const float* bout = (const float*)d_in[13];

    const int E = in_sizes[1] / 2;
    const int N = N_NODES;
    const int* src = ei;
    const int* dst = ei + E;

    char* p = (char*)d_ws;
    auto alloc = [&](size_t bytes) {
        char* r = p;
        p += (bytes + 15) & ~(size_t)15;
        return r;
    };
    int*            cursor = (int*)alloc(N * sizeof(int));
    unsigned short* bucket = (unsigned short*)alloc((size_t)N * CAP * 2);
    float*          dis    = (float*)alloc(N * sizeof(float));
    float*          xd     = (float*)alloc((size_t)N * 4 * sizeof(float));
    char*           hs     = (char*)alloc((size_t)N * 256);  // fp16 [n][f][b]
    float*          pc     = (float*)alloc(2240 * sizeof(float));

    // 1) zero cursor + fold constants
    zero_precomp_kernel<<<(N + 255) / 256, 256, 0, stream>>>(
        cursor, Wc1, bc1, Wl1, bl1, Wc2, bc2, Wl2, bl2, pc, N);

    // 2) bucket build
    fill_kernel<<<(E + 255) / 256, 256, 0, stream>>>(src, dst, cursor, bucket,
                                                     E);
    // 3) dis + xd
    dis_xd_kernel<<<(N + 255) / 256, 256, 0, stream>>>(cursor, x, dis,
                                                       (float4*)xd, N);
    // 4) layer 1 fused (agg + gates -> fp16 hs)
    s1h1_kernel<<<(N * 8 + 255) / 256, 256, 0, stream>>>(
        (const float4*)xd, dis, cursor, bucket, pc, hs, N);

    // 5) layer 2 fused (agg + gates + output projection), 16-deep window
    l2_agg_kernel<<<2048, 256, 0, stream>>>(hs, dis, cursor, bucket, pc, Wout,
                                            bout, (float*)d_out, N);
}

// Round 13
// 210.203 us; speedup vs baseline: 1.4992x; 1.0124x over previous
//
#include <hip/hip_runtime.h>
#include <hip/hip_fp16.h>
#include <stdint.h>

#define N_NODES 50000
#define BATCH 4
#define CAP 64  // max in-degree (deg ~ Poisson(16); P(>64) ~ 1e-10)

// ---------------------------------------------------------------------------
// Merged (all fill-independent): zero cursor + transpose x -> xT[n]={x[b][n]}
// + fold weight constants into pc.
//  pc[0..1023]    M0 = Wc2[0]@Wl2[0][:32]      pc[1024..2047]  M2 (gate 2)
//  pc[2048..2079] w0 = bc2[0]@Wl2[0]+bl2[0]    pc[2080..2111]  w2
//  pc[2112..2143] uz = Wc1[0]@Wl1[0]           pc[2144..2175]  vz
//  pc[2176..2207] uh (gate 2)                  pc[2208..2239]  vh
// (H=0 => reset gate dead; concat uses only rows 0..31 of each Wl)
// ---------------------------------------------------------------------------
__global__ void prep_kernel(int* __restrict__ cursor,
                            const float* __restrict__ x,
                            float4* __restrict__ xT,
                            const float* __restrict__ Wc1,
                            const float* __restrict__ bc1,
                            const float* __restrict__ Wl1,
                            const float* __restrict__ bl1,
                            const float* __restrict__ Wc2,
                            const float* __restrict__ bc2,
                            const float* __restrict__ Wl2,
                            const float* __restrict__ bl2,
                            float* __restrict__ pc, int N) {
    int i = blockIdx.x * blockDim.x + threadIdx.x;
    if (i < N) {
        cursor[i] = 0;
        xT[i] = make_float4(x[i], x[N + i], x[2 * N + i], x[3 * N + i]);
    }
    if (i >= 2240) return;
    if (i < 2048) {
        int g = i >> 10;
        int kf = i & 1023;
        int k = kf >> 5, f = kf & 31;
        int gate = g ? 2 : 0;
        float s = 0.0f;
        for (int j = 0; j < 32; ++j)
            s += Wc2[gate * 1024 + k * 32 + j] * Wl2[gate * 2048 + j * 32 + f];
        pc[i] = s;
    } else if (i < 2112) {
        int g = (i - 2048) >> 5;
        int f = i & 31;
        int gate = g ? 2 : 0;
        float s = bl2[gate * 32 + f];
        for (int j = 0; j < 32; ++j)
            s += bc2[gate * 32 + j] * Wl2[gate * 2048 + j * 32 + f];
        pc[i] = s;
    } else {
        int t = i - 2112;
        int which = t >> 5;
        int f = t & 31;
        int gate = (which >= 2) ? 2 : 0;
        if ((which & 1) == 0) {
            float s = 0.0f;
            for (int j = 0; j < 32; ++j)
                s += Wc1[gate * 32 + j] * Wl1[gate * 2048 + j * 32 + f];
            pc[i] = s;
        } else {
            float s = bl1[gate * 32 + f];
            for (int j = 0; j < 32; ++j)
                s += bc1[gate * 32 + j] * Wl1[gate * 2048 + j * 32 + f];
            pc[i] = s;
        }
    }
}

// ---------------------------------------------------------------------------
// Bucket CSR build, 4 edges/thread (int4 loads). After: cursor[d] = deg(d).
// ---------------------------------------------------------------------------
__global__ void fill_kernel(const int* __restrict__ src,
                            const int* __restrict__ dst,
                            int* __restrict__ cursor,
                            unsigned short* __restrict__ bucket, int E) {
    int t = blockIdx.x * blockDim.x + threadIdx.x;
    int e = t * 4;
    if (e + 4 <= E) {
        int4 s4 = *reinterpret_cast<const int4*>(src + e);
        int4 d4 = *reinterpret_cast<const int4*>(dst + e);
        int p0 = atomicAdd(&cursor[d4.x], 1);
        int p1 = atomicAdd(&cursor[d4.y], 1);
        int p2 = atomicAdd(&cursor[d4.z], 1);
        int p3 = atomicAdd(&cursor[d4.w], 1);
        if (p0 < CAP) bucket[d4.x * CAP + p0] = (unsigned short)s4.x;
        if (p1 < CAP) bucket[d4.y * CAP + p1] = (unsigned short)s4.y;
        if (p2 < CAP) bucket[d4.z * CAP + p2] = (unsigned short)s4.z;
        if (p3 < CAP) bucket[d4.w * CAP + p3] = (unsigned short)s4.w;
    } else {
        for (; e < E; ++e) {
            int d = dst[e];
            int pos = atomicAdd(&cursor[d], 1);
            if (pos < CAP) bucket[d * CAP + pos] = (unsigned short)src[e];
        }
    }
}

// ---------------------------------------------------------------------------
// Fused layer 1: rank-1 agg (8 lanes/node, xor-reduce; per-edge dis computed
// on the fly from deg) + folded gates -> hs[n][f][b] fp16.
// ---------------------------------------------------------------------------
__global__ void s1h1_kernel(const float4* __restrict__ xT,
                            const int* __restrict__ deg,
                            const unsigned short* __restrict__ bucket,
                            const float* __restrict__ pc,
                            char* __restrict__ hs, int N) {
    int idx = blockIdx.x * blockDim.x + threadIdx.x;
    int node = idx >> 3;
    if (node >= N) return;
    int j = idx & 7;
    int dgr = deg[node];
    int cnt = dgr > CAP ? CAP : dgr;
    float dnode = rsqrtf((float)(dgr + 1));
    float ax, ay, az, aw;
    if (j == 0) {
        float4 v = xT[node];  // self loop: x*dis
        ax = v.x * dnode; ay = v.y * dnode; az = v.z * dnode; aw = v.w * dnode;
    } else {
        ax = ay = az = aw = 0.f;
    }
    for (int i = j; i < cnt; i += 8) {
        int s = bucket[node * CAP + i];
        float ds = rsqrtf((float)(deg[s] + 1));
        float4 v = xT[s];
        ax += v.x * ds; ay += v.y * ds; az += v.z * ds; aw += v.w * ds;
    }
#pragma unroll
    for (int m = 4; m; m >>= 1) {
        ax += __shfl_xor(ax, m, 64);
        ay += __shfl_xor(ay, m, 64);
        az += __shfl_xor(az, m, 64);
        aw += __shfl_xor(aw, m, 64);
    }
    float t0 = ax * dnode, t1 = ay * dnode, t2 = az * dnode, t3 = aw * dnode;
#pragma unroll
    for (int m = 0; m < 4; ++m) {
        int f = j + 8 * m;
        float uz = pc[2112 + f], vz = pc[2144 + f];
        float uh = pc[2176 + f], vh = pc[2208 + f];
        float h0 = fmaxf((1.0f - 1.0f / (1.0f + expf(-(t0 * uz + vz)))) *
                         tanhf(t0 * uh + vh), 0.0f) * dnode;
        float h1 = fmaxf((1.0f - 1.0f / (1.0f + expf(-(t1 * uz + vz)))) *
                         tanhf(t1 * uh + vh), 0.0f) * dnode;
        float h2 = fmaxf((1.0f - 1.0f / (1.0f + expf(-(t2 * uz + vz)))) *
                         tanhf(t2 * uh + vh), 0.0f) * dnode;
        float h3 = fmaxf((1.0f - 1.0f / (1.0f + expf(-(t3 * uz + vz)))) *
                         tanhf(t3 * uh + vh), 0.0f) * dnode;
        __half2 lo = __floats2half2_rn(h0, h1);
        __half2 hi = __floats2half2_rn(h2, h3);
        uint2 u;
        u.x = *reinterpret_cast<unsigned int*>(&lo);
        u.y = *reinterpret_cast<unsigned int*>(&hi);
        *reinterpret_cast<uint2*>(hs + (size_t)node * 256 + f * 8) = u;
    }
}

// ---------------------------------------------------------------------------
// Layer-2 fused agg + gates + output projection. Grid-stride waves.
// Wave = node. Lane l: f=l&31, h=l>>5 owns batches {2h,2h+1} (half2 4B/edge).
// NEW: cross-node software pipeline — next node's {deg, bucket row, self row}
// are prefetched before the current node's gather ladder, hiding the serial
// row-load latency (vmcnt is issue-ordered: prefetch drains under gathers).
// Gather: 16/8/4/1 ladder (R11-proven). Tail: M-columns in VGPRs + wave-
// private LDS transpose.
// ---------------------------------------------------------------------------
__global__ __launch_bounds__(256) void l2_agg_kernel(
    const char* __restrict__ hs, const int* __restrict__ deg,
    const unsigned short* __restrict__ bucket, const float* __restrict__ pc,
    const float* __restrict__ Wout, const float* __restrict__ bout,
    float* __restrict__ out, int N) {
    __shared__ float2 sT[4][64];  // wave-private transpose scratch
    int wv = threadIdx.x >> 6;
    int lane = threadIdx.x & 63;
    int f = lane & 31;
    int h = lane >> 5;

    float wl0[32], wl2[32];
#pragma unroll
    for (int k = 0; k < 32; ++k) {
        wl0[k] = pc[k * 32 + f];          // M0 column f
        wl2[k] = pc[1024 + k * 32 + f];   // M2 column f
    }
    float w0 = pc[2048 + f], w2 = pc[2080 + f];
    float wf = Wout[f];
    float bo = bout[0];
    const char* hp = hs + f * 8 + h * 4;  // lane's half2 within a 256B row

    int wid = (blockIdx.x * blockDim.x + threadIdx.x) >> 6;
    int nw = (gridDim.x * blockDim.x) >> 6;
    if (wid >= N) return;

    // preload first node's state
    int dgr = deg[wid];
    unsigned int bidx = bucket[wid * CAP + lane];
    __half2 self = *(const __half2*)(hp + (size_t)wid * 256);

    for (int node = wid; node < N;) {
        int nxt = node + nw;
        // ---- prefetch next node's state (overlaps with this node's gathers)
        int ndgr = 0;
        unsigned int nbidx = 0;
        __half2 nself = __floats2half2_rn(0.f, 0.f);
        if (nxt < N) {
            ndgr = deg[nxt];
            nbidx = bucket[nxt * CAP + lane];
            nself = *(const __half2*)(hp + (size_t)nxt * 256);
        }

        int cnt = dgr > CAP ? CAP : dgr;
        float dn = rsqrtf((float)(dgr + 1));
        __half2 acc = self;  // self loop
        int i = 0;
        for (; i + 16 <= cnt; i += 16) {
            unsigned int o0 = __builtin_amdgcn_readlane(bidx, i) * 256u;
            unsigned int o1 = __builtin_amdgcn_readlane(bidx, i + 1) * 256u;
            unsigned int o2 = __builtin_amdgcn_readlane(bidx, i + 2) * 256u;
            unsigned int o3 = __builtin_amdgcn_readlane(bidx, i + 3) * 256u;
            unsigned int o4 = __builtin_amdgcn_readlane(bidx, i + 4) * 256u;
            unsigned int o5 = __builtin_amdgcn_readlane(bidx, i + 5) * 256u;
            unsigned int o6 = __builtin_amdgcn_readlane(bidx, i + 6) * 256u;
            unsigned int o7 = __builtin_amdgcn_readlane(bidx, i + 7) * 256u;
            unsigned int o8 = __builtin_amdgcn_readlane(bidx, i + 8) * 256u;
            unsigned int o9 = __builtin_amdgcn_readlane(bidx, i + 9) * 256u;
            unsigned int oa = __builtin_amdgcn_readlane(bidx, i + 10) * 256u;
            unsigned int ob = __builtin_amdgcn_readlane(bidx, i + 11) * 256u;
            unsigned int oc = __builtin_amdgcn_readlane(bidx, i + 12) * 256u;
            unsigned int od = __builtin_amdgcn_readlane(bidx, i + 13) * 256u;
            unsigned int oe = __builtin_amdgcn_readlane(bidx, i + 14) * 256u;
            unsigned int of_ = __builtin_amdgcn_readlane(bidx, i + 15) * 256u;
            __half2 v0 = *(const __half2*)(hp + o0);
            __half2 v1 = *(const __half2*)(hp + o1);
            __half2 v2 = *(const __half2*)(hp + o2);
            __half2 v3 = *(const __half2*)(hp + o3);
            __half2 v4 = *(const __half2*)(hp + o4);
            __half2 v5 = *(const __half2*)(hp + o5);
            __half2 v6 = *(const __half2*)(hp + o6);
            __half2 v7 = *(const __half2*)(hp + o7);
            __half2 v8 = *(const __half2*)(hp + o8);
            __half2 v9 = *(const __half2*)(hp + o9);
            __half2 va = *(const __half2*)(hp + oa);
            __half2 vb = *(const __half2*)(hp + ob);
            __half2 vc = *(const __half2*)(hp + oc);
            __half2 vd = *(const __half2*)(hp + od);
            __half2 ve = *(const __half2*)(hp + oe);
            __half2 vf = *(const __half2*)(hp + of_);
            __half2 s01 = __hadd2(v0, v1), s23 = __hadd2(v2, v3);
            __half2 s45 = __hadd2(v4, v5), s67 = __hadd2(v6, v7);
            __half2 s89 = __hadd2(v8, v9), sab = __hadd2(va, vb);
            __half2 scd = __hadd2(vc, vd), sef = __hadd2(ve, vf);
            __half2 t03 = __hadd2(s01, s23), t47 = __hadd2(s45, s67);
            __half2 t8b = __hadd2(s89, sab), tcf = __hadd2(scd, sef);
            acc = __hadd2(acc, __hadd2(__hadd2(t03, t47), __hadd2(t8b, tcf)));
        }
        if (i + 8 <= cnt) {
            unsigned int o0 = __builtin_amdgcn_readlane(bidx, i) * 256u;
            unsigned int o1 = __builtin_amdgcn_readlane(bidx, i + 1) * 256u;
            unsigned int o2 = __builtin_amdgcn_readlane(bidx, i + 2) * 256u;
            unsigned int o3 = __builtin_amdgcn_readlane(bidx, i + 3) * 256u;
            unsigned int o4 = __builtin_amdgcn_readlane(bidx, i + 4) * 256u;
            unsigned int o5 = __builtin_amdgcn_readlane(bidx, i + 5) * 256u;
            unsigned int o6 = __builtin_amdgcn_readlane(bidx, i + 6) * 256u;
            unsigned int o7 = __builtin_amdgcn_readlane(bidx, i + 7) * 256u;
            __half2 v0 = *(const __half2*)(hp + o0);
            __half2 v1 = *(const __half2*)(hp + o1);
            __half2 v2 = *(const __half2*)(hp + o2);
            __half2 v3 = *(const __half2*)(hp + o3);
            __half2 v4 = *(const __half2*)(hp + o4);
            __half2 v5 = *(const __half2*)(hp + o5);
            __half2 v6 = *(const __half2*)(hp + o6);
            __half2 v7 = *(const __half2*)(hp + o7);
            __half2 s01 = __hadd2(v0, v1), s23 = __hadd2(v2, v3);
            __half2 s45 = __hadd2(v4, v5), s67 = __hadd2(v6, v7);
            acc = __hadd2(acc, __hadd2(__hadd2(s01, s23), __hadd2(s45, s67)));
            i += 8;
        }
        if (i + 4 <= cnt) {
            unsigned int o0 = __builtin_amdgcn_readlane(bidx, i) * 256u;
            unsigned int o1 = __builtin_amdgcn_readlane(bidx, i + 1) * 256u;
            unsigned int o2 = __builtin_amdgcn_readlane(bidx, i + 2) * 256u;
            unsigned int o3 = __builtin_amdgcn_readlane(bidx, i + 3) * 256u;
            __half2 v0 = *(const __half2*)(hp + o0);
            __half2 v1 = *(const __half2*)(hp + o1);
            __half2 v2 = *(const __half2*)(hp + o2);
            __half2 v3 = *(const __half2*)(hp + o3);
            acc = __hadd2(acc, __hadd2(__hadd2(v0, v1), __hadd2(v2, v3)));
            i += 4;
        }
        for (; i < cnt; ++i) {
            unsigned int o = __builtin_amdgcn_readlane(bidx, i) * 256u;
            acc = __hadd2(acc, *(const __half2*)(hp + o));
        }
        float2 fa = __half22float2(acc);  // (T[2h][f], T[2h+1][f])

        // transpose via wave-private LDS (no barrier; in-wave DS ordering)
        sT[wv][lane] = fa;

        float sz0 = 0.f, sz1 = 0.f, sh0 = 0.f, sh1 = 0.f;
        const float2* tp = &sT[wv][h * 32];  // this half's 32 (T0,T1) pairs
#pragma unroll
        for (int k = 0; k < 32; k += 2) {
            float4 t2 = *(const float4*)&tp[k];  // broadcast read, 2 k's
            sz0 += t2.x * wl0[k];     sz1 += t2.y * wl0[k];
            sh0 += t2.x * wl2[k];     sh1 += t2.y * wl2[k];
            sz0 += t2.z * wl0[k + 1]; sz1 += t2.w * wl0[k + 1];
            sh0 += t2.z * wl2[k + 1]; sh1 += t2.w * wl2[k + 1];
        }
        float z0 = 1.0f / (1.0f + expf(-(dn * sz0 + w0)));
        float z1 = 1.0f / (1.0f + expf(-(dn * sz1 + w0)));
        float t0 = tanhf(dn * sh0 + w2);
        float t1 = tanhf(dn * sh1 + w2);
        float h20 = fmaxf((1.0f - z0) * t0, 0.0f);
        float h21 = fmaxf((1.0f - z1) * t1, 0.0f);

        float o0 = h20 * wf;
        float o1 = h21 * wf;
#pragma unroll
        for (int d = 16; d; d >>= 1) {  // reduce over f within each half
            o0 += __shfl_xor(o0, d, 64);
            o1 += __shfl_xor(o1, d, 64);
        }
        if (f == 0) {
            out[(size_t)(2 * h) * N + node] = o0 + bo;
            out[(size_t)(2 * h + 1) * N + node] = o1 + bo;
        }

        // rotate pipeline state
        node = nxt;
        dgr = ndgr;
        bidx = nbidx;
        self = nself;
    }
}

// ---------------------------------------------------------------------------

extern "C" void kernel_launch(void* const* d_in, const int* in_sizes, int n_in,
                              void* d_out, int out_size, void* d_ws,
                              size_t ws_size, hipStream_t stream) {
    const float* x    = (const float*)d_in[0];
    const int*   ei   = (const int*)d_in[1];
    const float* Wc1  = (const float*)d_in[2];
    const float* bc1  = (const float*)d_in[3];
    const float* Wl1  = (const float*)d_in[4];
    const float* bl1  = (const float*)d_in[5];
    // d_in[6] att1: softmax over 1 element == 1.0
    const float* Wc2  = (const float*)d_in[7];
    const float* bc2  = (const float*)d_in[8];
    const float* Wl2  = (const float*)d_in[9];
    const float* bl2  = (const float*)d_in[10];
    // d_in[11] att2 unused
    const float* Wout = (const float*)d_in[12];
    const float* bout = (const float*)d_in[13];

    const int E = in_sizes[1] / 2;
    const int N = N_NODES;
    const int* src = ei;
    const int* dst = ei + E;

    char* p = (char*)d_ws;
    auto alloc = [&](size_t bytes) {
        char* r = p;
        p += (bytes + 15) & ~(size_t)15;
        return r;
    };
    int*            cursor = (int*)alloc(N * sizeof(int));
    unsigned short* bucket = (unsigned short*)alloc((size_t)N * CAP * 2);
    float*          xT     = (float*)alloc((size_t)N * 4 * sizeof(float));
    char*           hs     = (char*)alloc((size_t)N * 256);  // fp16 [n][f][b]
    float*          pc     = (float*)alloc(2240 * sizeof(float));

    // 1) zero cursor + transpose x + fold constants
    prep_kernel<<<(N + 255) / 256, 256, 0, stream>>>(
        cursor, x, (float4*)xT, Wc1, bc1, Wl1, bl1, Wc2, bc2, Wl2, bl2, pc, N);

    // 2) bucket build, 4 edges/thread (cursor becomes deg)
    fill_kernel<<<(E / 4 + 255) / 256, 256, 0, stream>>>(src, dst, cursor,
                                                         bucket, E);
    // 3) layer 1 fused (agg + gates -> fp16 hs); dis computed on the fly
    s1h1_kernel<<<(N * 8 + 255) / 256, 256, 0, stream>>>(
        (const float4*)xT, cursor, bucket, pc, hs, N);

    // 4) layer 2 fused, 16-deep gather window + cross-node prefetch
    l2_agg_kernel<<<2048, 256, 0, stream>>>(hs, cursor, bucket, pc, Wout, bout,
                                            (float*)d_out, N);
}